// Round 5
// baseline (726.213 us; speedup 1.0000x reference)
//
#include <hip/hip_runtime.h>
#include <cstdint>
#include <cmath>

#define SS 2048
#define HH 1024

typedef __bf16 bf16_t;
typedef __bf16 bf16x8 __attribute__((ext_vector_type(8)));
typedef __bf16 bf16x4 __attribute__((ext_vector_type(4)));
typedef float  f32x4  __attribute__((ext_vector_type(4)));

union U32P { unsigned u; bf16_t h[2]; };

__device__ __forceinline__ void async_load16(const void* g, void* l) {
  __builtin_amdgcn_global_load_lds(
      (__attribute__((address_space(1))) void*)(g),
      (__attribute__((address_space(3))) void*)(l), 16, 0, 0);
}

// ---------------- fp32 -> bf16 convert ------------------------------------
__global__ __launch_bounds__(256) void cvt_kernel(const float* __restrict__ in,
                                                  bf16_t* __restrict__ out) {
  size_t i = (size_t)blockIdx.x * 256 + threadIdx.x;
  f32x4 v = ((const f32x4*)in)[i];
  bf16x4 o;
  o[0] = (bf16_t)v[0]; o[1] = (bf16_t)v[1]; o[2] = (bf16_t)v[2]; o[3] = (bf16_t)v[3];
  ((bf16x4*)out)[i] = o;
}

// ---------------- LayerNorm: fp32 in [4096,1024] -> bf16 out ---------------
__global__ __launch_bounds__(256) void ln_kernel(const float* __restrict__ x,
                                                 const float* __restrict__ w,
                                                 const float* __restrict__ b,
                                                 bf16_t* __restrict__ out) {
  const int row = blockIdx.x;
  const int tid = threadIdx.x;
  const f32x4 v = ((const f32x4*)(x + (size_t)row * HH))[tid];
  float s  = v[0] + v[1] + v[2] + v[3];
  float s2 = v[0]*v[0] + v[1]*v[1] + v[2]*v[2] + v[3]*v[3];
#pragma unroll
  for (int o = 1; o < 64; o <<= 1) { s += __shfl_xor(s, o); s2 += __shfl_xor(s2, o); }
  __shared__ float r1[4], r2[4];
  if ((tid & 63) == 0) { r1[tid >> 6] = s; r2[tid >> 6] = s2; }
  __syncthreads();
  float ts  = r1[0] + r1[1] + r1[2] + r1[3];
  float ts2 = r2[0] + r2[1] + r2[2] + r2[3];
  float mu  = ts * (1.0f / HH);
  float var = ts2 * (1.0f / HH) - mu * mu;
  float rstd = rsqrtf(var + 1e-5f);
  f32x4 wv = ((const f32x4*)w)[tid];
  f32x4 bv = ((const f32x4*)b)[tid];
  bf16x4 o;
#pragma unroll
  for (int j = 0; j < 4; ++j) o[j] = (bf16_t)((v[j] - mu) * rstd * wv[j] + bv[j]);
  ((bf16x4*)(out + (size_t)row * HH))[tid] = o;
}

__device__ __forceinline__ float gelu_f(float x) {
  return 0.5f * x * (1.0f + erff(x * 0.70710678118654752f));
}

// ---- fused residual add: x += p0 + p1 + bias -------------------------------
__global__ __launch_bounds__(256) void fuse_add(float* __restrict__ x,
                                                const bf16_t* __restrict__ p0,
                                                const bf16_t* __restrict__ p1,
                                                const float* __restrict__ bias) {
  size_t i = (size_t)blockIdx.x * 256 + threadIdx.x;
  f32x4 xv = ((f32x4*)x)[i];
  bf16x4 a = ((const bf16x4*)p0)[i];
  bf16x4 b4 = ((const bf16x4*)p1)[i];
  f32x4 bv = ((const f32x4*)bias)[i & 255];
#pragma unroll
  for (int j = 0; j < 4; ++j) xv[j] += (float)a[j] + (float)b4[j] + bv[j];
  ((f32x4*)x)[i] = xv;
}

// ---------------- GEMM: C = A * W^T + bias; EPI 0=bias, 1=bias+gelu ---------
template <int EPI>
__global__ __launch_bounds__(256) void gemm_bt(const bf16_t* __restrict__ A,
                                               const bf16_t* __restrict__ W,
                                               const float* __restrict__ bias,
                                               bf16_t* __restrict__ outb,
                                               int M, int N, int K) {
  __shared__ __align__(16) bf16_t As[128 * 64];
  __shared__ __align__(16) bf16_t Bs[128 * 64];
  const int tid = threadIdx.x;
  const int w = tid >> 6, lane = tid & 63;
  const int m16 = lane & 15, quad = lane >> 4;
  const int wm = w & 1, wn = w >> 1;
  const int n0 = blockIdx.x * 128, m0 = blockIdx.y * 128;

  f32x4 acc[4][4];
#pragma unroll
  for (int i = 0; i < 4; ++i)
#pragma unroll
    for (int j = 0; j < 4; ++j) acc[i][j] = (f32x4){0.f, 0.f, 0.f, 0.f};

  int rowi[4], gci[4];
#pragma unroll
  for (int i = 0; i < 4; ++i) {
    int p = (w * 4 + i) * 64 + lane;
    rowi[i] = p >> 3;
    gci[i] = ((lane & 7) ^ (rowi[i] & 7)) * 8;
  }

  for (int kt = 0; kt < K; kt += 64) {
    __syncthreads();
#pragma unroll
    for (int i = 0; i < 4; ++i) {
      async_load16(A + (size_t)(m0 + rowi[i]) * K + kt + gci[i], &As[(w * 4 + i) * 512]);
      async_load16(W + (size_t)(n0 + rowi[i]) * K + kt + gci[i], &Bs[(w * 4 + i) * 512]);
    }
    __syncthreads();
#pragma unroll
    for (int kk = 0; kk < 2; ++kk) {
      bf16x8 af[4], bfv[4];
#pragma unroll
      for (int mi = 0; mi < 4; ++mi) {
        int row = wm * 64 + mi * 16 + m16;
        int cpos = (kk * 4 + quad) ^ (row & 7);
        af[mi] = *(const bf16x8*)&As[row * 64 + cpos * 8];
      }
#pragma unroll
      for (int ni = 0; ni < 4; ++ni) {
        int row = wn * 64 + ni * 16 + m16;
        int cpos = (kk * 4 + quad) ^ (row & 7);
        bfv[ni] = *(const bf16x8*)&Bs[row * 64 + cpos * 8];
      }
#pragma unroll
      for (int mi = 0; mi < 4; ++mi)
#pragma unroll
        for (int ni = 0; ni < 4; ++ni)
          acc[mi][ni] = __builtin_amdgcn_mfma_f32_16x16x32_bf16(af[mi], bfv[ni],
                                                                acc[mi][ni], 0, 0, 0);
    }
  }

#pragma unroll
  for (int ni = 0; ni < 4; ++ni) {
    int col = n0 + wn * 64 + ni * 16 + m16;
    float bv = bias[col];
#pragma unroll
    for (int mi = 0; mi < 4; ++mi) {
      int rowb = m0 + wm * 64 + mi * 16 + quad * 4;
#pragma unroll
      for (int r = 0; r < 4; ++r) {
        size_t idx = (size_t)(rowb + r) * N + col;
        float v = acc[mi][ni][r] + bv;
        if constexpr (EPI == 1) v = gelu_f(v);
        outb[idx] = (bf16_t)v;
      }
    }
  }
}

// ---- split-K=2 GEMM -> bf16 partial buffers (no bias) ----------------------
__global__ __launch_bounds__(256) void gemm_sk2(const bf16_t* __restrict__ A,
                                                const bf16_t* __restrict__ W,
                                                bf16_t* __restrict__ p0,
                                                bf16_t* __restrict__ p1,
                                                int M, int N, int K) {
  __shared__ __align__(16) bf16_t As[128 * 64];
  __shared__ __align__(16) bf16_t Bs[128 * 64];
  const int tid = threadIdx.x;
  const int w = tid >> 6, lane = tid & 63;
  const int m16 = lane & 15, quad = lane >> 4;
  const int wm = w & 1, wn = w >> 1;
  const int n0 = blockIdx.x * 128, m0 = blockIdx.y * 128;
  const int z = blockIdx.z;
  const int kbeg = z * (K >> 1), kend = kbeg + (K >> 1);
  bf16_t* outb = z ? p1 : p0;

  f32x4 acc[4][4];
#pragma unroll
  for (int i = 0; i < 4; ++i)
#pragma unroll
    for (int j = 0; j < 4; ++j) acc[i][j] = (f32x4){0.f, 0.f, 0.f, 0.f};

  int rowi[4], gci[4];
#pragma unroll
  for (int i = 0; i < 4; ++i) {
    int p = (w * 4 + i) * 64 + lane;
    rowi[i] = p >> 3;
    gci[i] = ((lane & 7) ^ (rowi[i] & 7)) * 8;
  }

  for (int kt = kbeg; kt < kend; kt += 64) {
    __syncthreads();
#pragma unroll
    for (int i = 0; i < 4; ++i) {
      async_load16(A + (size_t)(m0 + rowi[i]) * K + kt + gci[i], &As[(w * 4 + i) * 512]);
      async_load16(W + (size_t)(n0 + rowi[i]) * K + kt + gci[i], &Bs[(w * 4 + i) * 512]);
    }
    __syncthreads();
#pragma unroll
    for (int kk = 0; kk < 2; ++kk) {
      bf16x8 af[4], bfv[4];
#pragma unroll
      for (int mi = 0; mi < 4; ++mi) {
        int row = wm * 64 + mi * 16 + m16;
        int cpos = (kk * 4 + quad) ^ (row & 7);
        af[mi] = *(const bf16x8*)&As[row * 64 + cpos * 8];
      }
#pragma unroll
      for (int ni = 0; ni < 4; ++ni) {
        int row = wn * 64 + ni * 16 + m16;
        int cpos = (kk * 4 + quad) ^ (row & 7);
        bfv[ni] = *(const bf16x8*)&Bs[row * 64 + cpos * 8];
      }
#pragma unroll
      for (int mi = 0; mi < 4; ++mi)
#pragma unroll
        for (int ni = 0; ni < 4; ++ni)
          acc[mi][ni] = __builtin_amdgcn_mfma_f32_16x16x32_bf16(af[mi], bfv[ni],
                                                                acc[mi][ni], 0, 0, 0);
    }
  }

#pragma unroll
  for (int ni = 0; ni < 4; ++ni) {
    int col = n0 + wn * 64 + ni * 16 + m16;
#pragma unroll
    for (int mi = 0; mi < 4; ++mi) {
      int rowb = m0 + wm * 64 + mi * 16 + quad * 4;
#pragma unroll
      for (int r = 0; r < 4; ++r) {
        size_t idx = (size_t)(rowb + r) * N + col;
        outb[idx] = (bf16_t)acc[mi][ni][r];
      }
    }
  }
}

// ---------------- Flash attention v5: stateless softmax, k-split x2 ---------
// Analytic max (p = 2^(C*z + slope2*(k-q)), diag term >= 1) makes partial
// sums over any kt-subset associative -> split each (bh,qt) into 2 chunks
// handled by different blocks; combine kernel sums O and l. Equalizes block
// durations (max 16 iters) so the grid doesn't drain to 1 block/CU.
__global__ __launch_bounds__(256, 4) void attn_part(const bf16_t* __restrict__ qkv,
                                                    bf16_t* __restrict__ P0,
                                                    bf16_t* __restrict__ P1,
                                                    float* __restrict__ lbuf) {
  const int y = blockIdx.y;
  const int qt = 31 - (y >> 1);     // heavy q-tiles first
  const int c = y & 1;              // k-chunk 0/1
  const int bh = blockIdx.x;        // b*16 + h
  const int b = bh >> 4, h = bh & 15;
  const int tid = threadIdx.x;
  const int w = tid >> 6, lane = tid & 63;
  const int m16 = lane & 15, quad = lane >> 4;
  const int pid = bh * 32 + qt;

  __shared__ __align__(16) bf16_t Vt[2][64 * 72];
  __shared__ __align__(16) bf16_t Pl[4][16 * 72];

  // slope_h = 2^(-0.5*(h+1)); slope2 = slope_h * log2(e)   [slope bug fixed]
  const float slope2 = __builtin_amdgcn_exp2f(-0.5f * (float)(h + 1))
                       * 1.4426950408889634f;
  // ALiBi window: keep tile iff slope2*((qt-kt)*64-63) <= 30
  const int wt = (int)((30.0f / slope2 + 63.0f) * 0.015625f);
  const int kt0 = (qt - wt > 0) ? (qt - wt) : 0;
  const int len = qt + 1 - kt0;
  const int half = (len + 1) >> 1;
  const int ka = c ? (kt0 + half) : kt0;
  const int kb = c ? (qt + 1) : (kt0 + half);

  const int q_abs = qt * 64 + w * 16 + m16;
  float alkb[16];
#pragma unroll
  for (int kn = 0; kn < 4; ++kn)
#pragma unroll
    for (int r = 0; r < 4; ++r)
      alkb[kn * 4 + r] = slope2 * (float)(ka * 64 + kn * 16 + quad * 4 + r - q_abs);
  const float d64 = slope2 * 64.0f;

  const int qrow = qt * 64 + w * 16 + m16;
  const bf16_t* qbase = qkv + (size_t)(b * SS + qrow) * 3072 + h * 64;
  const bf16x8 bq0 = *(const bf16x8*)(qbase + quad * 8);
  const bf16x8 bq1 = *(const bf16x8*)(qbase + 32 + quad * 8);

  const bf16_t* kbase = qkv + (size_t)(b * SS + m16) * 3072 + 1024 + h * 64 + quad * 8;
  const int kp2 = (tid & 31) * 2, vd0 = (tid >> 5) * 8;
  const bf16_t* vsrc = qkv + (size_t)(b * SS + kp2) * 3072 + 2048 + h * 64 + vd0;
  const int ql = w * 16 + m16;
  constexpr float C = 0.18033688011112042f;  // log2(e)/8

  f32x4 acc[4];
#pragma unroll
  for (int i = 0; i < 4; ++i) acc[i] = (f32x4){0.f, 0.f, 0.f, 0.f};
  float rs_l = 0.f;

  // preload tile ka (if chunk empty, loads are harmless in-ws reads, unused)
  bf16x8 ak[4][2], v0, v1;
  {
    const bf16_t* kb2 = kbase + (size_t)ka * 64 * 3072;
#pragma unroll
    for (int kn = 0; kn < 4; ++kn) {
      ak[kn][0] = *(const bf16x8*)(kb2 + (size_t)(kn * 16) * 3072);
      ak[kn][1] = *(const bf16x8*)(kb2 + (size_t)(kn * 16) * 3072 + 32);
    }
    const bf16_t* vs = vsrc + (size_t)ka * 64 * 3072;
    v0 = *(const bf16x8*)(vs);
    v1 = *(const bf16x8*)(vs + 3072);
  }
#pragma unroll
  for (int j = 0; j < 8; ++j) {
    U32P pk; pk.h[0] = v0[j]; pk.h[1] = v1[j];
    *(unsigned*)&Vt[ka & 1][(vd0 + j) * 72 + kp2] = pk.u;
  }

  for (int kt = ka; kt < kb; ++kt) {
    __syncthreads();

    bf16x8 nk[4][2], nv0 = v0, nv1 = v1;
    if (kt + 1 < kb) {
      const bf16_t* kb2 = kbase + (size_t)(kt + 1) * 64 * 3072;
#pragma unroll
      for (int kn = 0; kn < 4; ++kn) {
        nk[kn][0] = *(const bf16x8*)(kb2 + (size_t)(kn * 16) * 3072);
        nk[kn][1] = *(const bf16x8*)(kb2 + (size_t)(kn * 16) * 3072 + 32);
      }
      const bf16_t* nsrc = vsrc + (size_t)(kt + 1) * 64 * 3072;
      nv0 = *(const bf16x8*)(nsrc);
      nv1 = *(const bf16x8*)(nsrc + 3072);
    } else {
#pragma unroll
      for (int kn = 0; kn < 4; ++kn) { nk[kn][0] = ak[kn][0]; nk[kn][1] = ak[kn][1]; }
    }

    float p[16];
    const bool diag = (kt == qt);
#pragma unroll
    for (int kn = 0; kn < 4; ++kn) {
      f32x4 z = (f32x4){0.f, 0.f, 0.f, 0.f};
      z = __builtin_amdgcn_mfma_f32_16x16x32_bf16(ak[kn][0], bq0, z, 0, 0, 0);
      z = __builtin_amdgcn_mfma_f32_16x16x32_bf16(ak[kn][1], bq1, z, 0, 0, 0);
#pragma unroll
      for (int r = 0; r < 4; ++r) {
        float s = fmaf(z[r], C, alkb[kn * 4 + r]);
        if (diag) {
          int kl = kn * 16 + quad * 4 + r;
          if (kl > ql) s = -INFINITY;
        }
        float e = __builtin_amdgcn_exp2f(s);
        p[kn * 4 + r] = e;
        rs_l += e;
      }
    }
#pragma unroll
    for (int i = 0; i < 16; ++i) alkb[i] += d64;

#pragma unroll
    for (int kn = 0; kn < 4; ++kn) {
      U32P a2, c2;
      a2.h[0] = (bf16_t)p[kn * 4 + 0]; a2.h[1] = (bf16_t)p[kn * 4 + 1];
      c2.h[0] = (bf16_t)p[kn * 4 + 2]; c2.h[1] = (bf16_t)p[kn * 4 + 3];
      uint2 pk; pk.x = a2.u; pk.y = c2.u;
      *(uint2*)&Pl[w][m16 * 72 + kn * 16 + quad * 4] = pk;
    }
    const bf16_t* vt = &Vt[kt & 1][0];
    bf16x8 bp0 = *(const bf16x8*)&Pl[w][m16 * 72 + quad * 8];
    bf16x8 bp1 = *(const bf16x8*)&Pl[w][m16 * 72 + 32 + quad * 8];
#pragma unroll
    for (int ni = 0; ni < 4; ++ni) {
      bf16x8 av0 = *(const bf16x8*)&vt[(ni * 16 + m16) * 72 + quad * 8];
      bf16x8 av1 = *(const bf16x8*)&vt[(ni * 16 + m16) * 72 + 32 + quad * 8];
      acc[ni] = __builtin_amdgcn_mfma_f32_16x16x32_bf16(av0, bp0, acc[ni], 0, 0, 0);
      acc[ni] = __builtin_amdgcn_mfma_f32_16x16x32_bf16(av1, bp1, acc[ni], 0, 0, 0);
    }

    if (kt + 1 < kb) {
#pragma unroll
      for (int j = 0; j < 8; ++j) {
        U32P pk; pk.h[0] = nv0[j]; pk.h[1] = nv1[j];
        *(unsigned*)&Vt[(kt + 1) & 1][(vd0 + j) * 72 + kp2] = pk.u;
      }
    }
#pragma unroll
    for (int kn = 0; kn < 4; ++kn) { ak[kn][0] = nk[kn][0]; ak[kn][1] = nk[kn][1]; }
    v0 = nv0; v1 = nv1;
  }

  // epilogue: write UN-normalized O partial (q-major 64x64) + per-q l
  rs_l += __shfl_xor(rs_l, 16);
  rs_l += __shfl_xor(rs_l, 32);
  bf16_t* ob = (c ? P1 : P0) + (size_t)pid * 4096 + (size_t)(w * 16 + m16) * 64;
#pragma unroll
  for (int ni = 0; ni < 4; ++ni) {
    U32P a2, c2;
    a2.h[0] = (bf16_t)acc[ni][0]; a2.h[1] = (bf16_t)acc[ni][1];
    c2.h[0] = (bf16_t)acc[ni][2]; c2.h[1] = (bf16_t)acc[ni][3];
    uint2 pk; pk.x = a2.u; pk.y = c2.u;
    *(uint2*)(ob + ni * 16 + quad * 4) = pk;
  }
  if (quad == 0) lbuf[(size_t)c * 65536 + (size_t)pid * 64 + w * 16 + m16] = rs_l;
}

// ---- combine: ctx[q][d] = (O0+O1)/(l0+l1) ----------------------------------
__global__ __launch_bounds__(256) void attn_comb(const bf16_t* __restrict__ P0,
                                                 const bf16_t* __restrict__ P1,
                                                 const float* __restrict__ lbuf,
                                                 bf16_t* __restrict__ ctx) {
  const int pid = blockIdx.x;  // bh*32 + qt
  const int bh = pid >> 5, qt = pid & 31;
  const int b = bh >> 4, h = bh & 15;
  const int t = threadIdx.x;
  const int q = t >> 2, j = (t & 3) * 16;
  const float inv = 1.0f / (lbuf[(size_t)pid * 64 + q] +
                            lbuf[65536 + (size_t)pid * 64 + q]);
  const bf16_t* a = P0 + (size_t)pid * 4096 + q * 64 + j;
  const bf16_t* c = P1 + (size_t)pid * 4096 + q * 64 + j;
  bf16x8 x0 = *(const bf16x8*)a, x1 = *(const bf16x8*)(a + 8);
  bf16x8 y0 = *(const bf16x8*)c, y1 = *(const bf16x8*)(c + 8);
  bf16x8 o0, o1;
#pragma unroll
  for (int i = 0; i < 8; ++i) {
    o0[i] = (bf16_t)(((float)x0[i] + (float)y0[i]) * inv);
    o1[i] = (bf16_t)(((float)x1[i] + (float)y1[i]) * inv);
  }
  bf16_t* ob = ctx + (size_t)(b * SS + qt * 64 + q) * 1024 + h * 64 + j;
  *(bf16x8*)ob = o0;
  *(bf16x8*)(ob + 8) = o1;
}

// ---------------------------------------------------------------------------
extern "C" void kernel_launch(void* const* d_in, const int* in_sizes, int n_in,
                              void* d_out, int out_size, void* d_ws, size_t ws_size,
                              hipStream_t stream) {
  const float* hs    = (const float*)d_in[0];
  const float* qkvw  = (const float*)d_in[2];
  const float* qkvb  = (const float*)d_in[3];
  const float* dw    = (const float*)d_in[4];
  const float* db    = (const float*)d_in[5];
  const float* w1    = (const float*)d_in[6];
  const float* b1    = (const float*)d_in[7];
  const float* w2    = (const float*)d_in[8];
  const float* b2    = (const float*)d_in[9];
  const float* ln1w  = (const float*)d_in[10];
  const float* ln1b  = (const float*)d_in[11];
  const float* ln2w  = (const float*)d_in[12];
  const float* ln2b  = (const float*)d_in[13];
  float* x = (float*)d_out;  // residual stream, fp32 [4096,1024]

  char* ws = (char*)d_ws;   // per-layer weight regions (re-converted each layer)
  bf16_t* wq = (bf16_t*)(ws + 0);          // 3072*1024 bf16
  bf16_t* wd = (bf16_t*)(ws + 6291456);    // 1024*1024
  bf16_t* w1c = (bf16_t*)(ws + 8388608);   // 4096*1024
  bf16_t* w2c = (bf16_t*)(ws + 16777216);  // 1024*4096
  bf16_t* hb  = (bf16_t*)(ws + 25165824);  // 4096*1024 (ln out / mlp2 partial0)
  bf16_t* qm  = (bf16_t*)(ws + 33554432);  // qkv(25MB) / mlp-mid(33.5MB) / dense partials
  bf16_t* cx  = (bf16_t*)(ws + 67108864);  // 4096*1024 (attn ctx / mlp2 partial1)
  bf16_t* P0  = (bf16_t*)(ws + 75497472);  // attn partials chunk0 (8.39MB)
  bf16_t* P1  = (bf16_t*)(ws + 83886080);  // chunk1 (8.39MB)
  float*  lb  = (float*)(ws + 92274688);   // l partials (0.52MB)
  bf16_t* dp0 = qm;                         // dense partials alias qm
  bf16_t* dp1 = qm + (size_t)4096 * 1024;

  hipMemcpyAsync(x, hs, (size_t)4096 * 1024 * 4, hipMemcpyDeviceToDevice, stream);

  for (int l = 0; l < 2; ++l) {
    // per-layer weight conversion (frees 25MB for attn partials)
    cvt_kernel<<<3072, 256, 0, stream>>>(qkvw + (size_t)l * 3145728, wq);
    cvt_kernel<<<1024, 256, 0, stream>>>(dw + (size_t)l * 1048576, wd);
    cvt_kernel<<<4096, 256, 0, stream>>>(w1 + (size_t)l * 4194304, w1c);
    cvt_kernel<<<4096, 256, 0, stream>>>(w2 + (size_t)l * 4194304, w2c);

    ln_kernel<<<4096, 256, 0, stream>>>(x, ln1w + l * 1024, ln1b + l * 1024, hb);
    gemm_bt<0><<<dim3(24, 32), 256, 0, stream>>>(hb, wq, qkvb + l * 3072, qm,
                                                 4096, 3072, 1024);
    attn_part<<<dim3(32, 64), 256, 0, stream>>>(qm, P0, P1, lb);
    attn_comb<<<1024, 256, 0, stream>>>(P0, P1, lb, cx);
    gemm_sk2<<<dim3(8, 32, 2), 256, 0, stream>>>(cx, wd, dp0, dp1, 4096, 1024, 1024);
    fuse_add<<<4096, 256, 0, stream>>>(x, dp0, dp1, db + l * 1024);
    ln_kernel<<<4096, 256, 0, stream>>>(x, ln2w + l * 1024, ln2b + l * 1024, hb);
    gemm_bt<1><<<dim3(32, 32), 256, 0, stream>>>(hb, w1c, b1 + l * 4096, qm,
                                                 4096, 4096, 1024);
    gemm_sk2<<<dim3(8, 32, 2), 256, 0, stream>>>(qm, w2c, hb, cx, 4096, 1024, 4096);
    fuse_add<<<4096, 256, 0, stream>>>(x, hb, cx, b2 + l * 1024);
  }
}